// Round 1
// baseline (235.979 us; speedup 1.0000x reference)
//
#include <hip/hip_runtime.h>

typedef __bf16 bf16;
typedef __bf16 bf16x4 __attribute__((ext_vector_type(4)));
typedef __bf16 bf16x8 __attribute__((ext_vector_type(8)));
typedef float f32x4 __attribute__((ext_vector_type(4)));

#define MFMA16(A, B, C) __builtin_amdgcn_mfma_f32_16x16x32_bf16(A, B, C, 0, 0, 0)

// 2^x via v_exp_f32 (input already in log2 domain). s_nop covers the
// trans->VALU dependent-read wait state.
static __device__ __forceinline__ float fast_exp2(float x) {
  float r;
  asm volatile("v_exp_f32 %0, %1\n\ts_nop 0" : "=v"(r) : "v"(x));
  return r;
}

// ---------------------------------------------------------------------------
// Kernel 1: W (256x256 fp32, [k][n]) -> Wt bf16 [p][n][k] so that MFMA
// B-fragments (8 consecutive k for fixed n) are 16B-contiguous loads.
// Coalesced reads (consecutive n), scattered bf16 writes (tiny, L2-absorbed).
// ---------------------------------------------------------------------------
__global__ __launch_bounds__(256) void prep_wt(const float* __restrict__ Wq,
                                               const float* __restrict__ Wk,
                                               const float* __restrict__ Wv,
                                               bf16* __restrict__ Wt) {
  const int idx = blockIdx.x * 256 + threadIdx.x;  // 0..196607
  const int p = idx >> 16;
  const int rem = idx & 65535;     // = k*256 + n
  const int k = rem >> 8;
  const int n = rem & 255;
  const float* W = (p == 0) ? Wq : ((p == 1) ? Wk : Wv);
  Wt[p * 65536 + n * 256 + k] = (bf16)W[rem];
}

// ---------------------------------------------------------------------------
// Kernel 2: QKV projection. Block = 64 rows of x * full 256 cols for one of
// {Q,K,V}. x tile staged as bf16 in LDS (+8 pad breaks ds_read_b128 bank
// aliasing); W fragments straight from L2-hot Wt. V stored transposed
// (Vt[b][d][s]) so the flash kernel's PV B-fragments are contiguous.
// ---------------------------------------------------------------------------
__global__ __launch_bounds__(256, 2) void proj_qkv(
    const float* __restrict__ x, const bf16* __restrict__ Wt,
    const float* __restrict__ bq, const float* __restrict__ bk,
    const float* __restrict__ bv, bf16* __restrict__ Q, bf16* __restrict__ K,
    bf16* __restrict__ Vt) {
  __shared__ __align__(16) bf16 xs[64][264];  // 33 KB
  const int t = threadIdx.x;
  const int tile = blockIdx.x;  // 0..255 (row tiles of 64 over 16384)
  const int p = blockIdx.y;     // 0=Q 1=K 2=V
  const int rowbase = tile * 64;

  {  // stage x tile -> bf16 LDS. 4 rows/pass * 16 passes, float4 loads.
    const int rr = t >> 6;
    const int c4 = (t & 63) * 4;
#pragma unroll 4
    for (int i = 0; i < 16; ++i) {
      const int r = rr + i * 4;
      const float4 v = *(const float4*)&x[(rowbase + r) * 256 + c4];
      bf16x4 h;
      h[0] = (bf16)v.x; h[1] = (bf16)v.y; h[2] = (bf16)v.z; h[3] = (bf16)v.w;
      *(bf16x4*)&xs[r][c4] = h;
    }
  }
  __syncthreads();

  const int lane = t & 63, w = t >> 6;
  const int l16 = lane & 15, quad = lane >> 4;

  bf16x8 a[8];  // persistent A-fragments: wave's 16 rows, K=256
#pragma unroll
  for (int kt = 0; kt < 8; ++kt)
    a[kt] = *(const bf16x8*)&xs[w * 16 + l16][kt * 32 + quad * 8];

  const bf16* Wp = Wt + p * 65536;
  f32x4 acc[16];
#pragma unroll
  for (int nt = 0; nt < 16; ++nt) acc[nt] = f32x4{0.f, 0.f, 0.f, 0.f};
#pragma unroll
  for (int kt = 0; kt < 8; ++kt) {
#pragma unroll
    for (int nt = 0; nt < 16; ++nt) {  // 16 independent MFMAs back-to-back
      const bf16x8 bf = *(const bf16x8*)&Wp[(nt * 16 + l16) * 256 + kt * 32 + quad * 8];
      acc[nt] = MFMA16(a[kt], bf, acc[nt]);
    }
  }

  const float* bias = (p == 0) ? bq : ((p == 1) ? bk : bv);
  bf16* dst01 = (p == 0) ? Q : K;
#pragma unroll
  for (int nt = 0; nt < 16; ++nt) {
    const int n = nt * 16 + l16;
    const float bb = bias[n];
#pragma unroll
    for (int r = 0; r < 4; ++r) {
      // C/D layout: row = quad*4 + r (within wave's 16 rows), col = l16
      const int row = rowbase + w * 16 + quad * 4 + r;
      const bf16 hv = (bf16)(acc[nt][r] + bb);
      if (p < 2) {
        dst01[row * 256 + n] = hv;
      } else {
        const int bb2 = row >> 11, s = row & 2047;
        Vt[bb2 * 524288 + n * 2048 + s] = hv;  // transposed store
      }
    }
  }
}

// ---------------------------------------------------------------------------
// Kernel 3: flash attention. Block = (batch, 64-row Q tile); 4 waves, each
// owning 16 Q rows with Q frags + O accumulator resident in VGPRs.
// Per iteration: stage 128-key K tile + Vt tile into LDS, S = Q@K^T via MFMA,
// online softmax (C-layout rows = quad*4+r, 16-lane shfl_xor row reductions),
// P transposed to A-layout through padded per-wave LDS, O += P@V.
// LDS: 66+68+17 = 151 KB static (gfx950 has 160 KB/WG). Grid 256 = 1 blk/CU.
// ---------------------------------------------------------------------------
__global__ __launch_bounds__(256, 1) void flash_attn(
    const bf16* __restrict__ Q, const bf16* __restrict__ K,
    const bf16* __restrict__ Vt, float* __restrict__ out) {
  __shared__ __align__(16) bf16 ks[128][264];    // K tile [n][k], +8 pad
  __shared__ __align__(16) bf16 vs[256][136];    // Vt tile [d][n], +8 pad
  __shared__ __align__(16) bf16 ps[4][16][136];  // per-wave P, +8 pad
  const int t = threadIdx.x;
  const int lane = t & 63, w = t >> 6;
  const int l16 = lane & 15, quad = lane >> 4;
  const int b = blockIdx.y, qt = blockIdx.x;

  const int qrow = b * 2048 + qt * 64 + w * 16 + l16;
  bf16x8 qf[8];
#pragma unroll
  for (int kt = 0; kt < 8; ++kt)
    qf[kt] = *(const bf16x8*)&Q[qrow * 256 + kt * 32 + quad * 8];

  f32x4 o[16];
#pragma unroll
  for (int dt = 0; dt < 16; ++dt) o[dt] = f32x4{0.f, 0.f, 0.f, 0.f};
  float mrun[4], lrun[4];
#pragma unroll
  for (int r = 0; r < 4; ++r) { mrun[r] = -1e30f; lrun[r] = 0.f; }
  const float kScale = 0.0625f * 1.4426950408889634f;  // 1/sqrt(256) * log2(e)

  const int srr = t >> 5, sc8 = (t & 31) * 8;  // K staging: 8 rows/pass
  const int vrr = t >> 4, vc8 = (t & 15) * 8;  // V staging: 16 rows/pass

  for (int it = 0; it < 16; ++it) {
    const int n0 = it * 128;
    const bf16* kb = K + (b * 2048 + n0) * 256;
#pragma unroll 4
    for (int i = 0; i < 16; ++i) {
      const int r = srr + i * 8;
      *(bf16x8*)&ks[r][sc8] = *(const bf16x8*)&kb[r * 256 + sc8];
    }
    const bf16* vb = Vt + b * 524288 + n0;
#pragma unroll 4
    for (int i = 0; i < 16; ++i) {
      const int d = vrr + i * 16;
      *(bf16x8*)&vs[d][vc8] = *(const bf16x8*)&vb[d * 2048 + vc8];
    }
    __syncthreads();

    // ---- S = Q @ K^T (64x128 per block, 16x128 per wave) ----
    f32x4 s[8];
#pragma unroll
    for (int j = 0; j < 8; ++j) s[j] = f32x4{0.f, 0.f, 0.f, 0.f};
#pragma unroll
    for (int kt = 0; kt < 8; ++kt) {
#pragma unroll
      for (int j = 0; j < 8; ++j) {  // 8 independent accumulator chains
        const bf16x8 kf = *(const bf16x8*)&ks[j * 16 + l16][kt * 32 + quad * 8];
        s[j] = MFMA16(qf[kt], kf, s[j]);
      }
    }

    // ---- online softmax over this 128-key chunk ----
    float cmax[4];
#pragma unroll
    for (int r = 0; r < 4; ++r) cmax[r] = -1e30f;
#pragma unroll
    for (int j = 0; j < 8; ++j)
#pragma unroll
      for (int r = 0; r < 4; ++r) {
        s[j][r] *= kScale;  // scaled score in log2 domain
        cmax[r] = fmaxf(cmax[r], s[j][r]);
      }
#pragma unroll
    for (int r = 0; r < 4; ++r) {  // row max across the 16 lanes of the quad
      cmax[r] = fmaxf(cmax[r], __shfl_xor(cmax[r], 1));
      cmax[r] = fmaxf(cmax[r], __shfl_xor(cmax[r], 2));
      cmax[r] = fmaxf(cmax[r], __shfl_xor(cmax[r], 4));
      cmax[r] = fmaxf(cmax[r], __shfl_xor(cmax[r], 8));
    }
    float alpha[4], psum[4];
#pragma unroll
    for (int r = 0; r < 4; ++r) {
      const float mnew = fmaxf(mrun[r], cmax[r]);
      alpha[r] = fast_exp2(mrun[r] - mnew);
      mrun[r] = mnew;
      psum[r] = 0.f;
    }
#pragma unroll
    for (int j = 0; j < 8; ++j) {
#pragma unroll
      for (int r = 0; r < 4; ++r) {
        const float pv = fast_exp2(s[j][r] - mrun[r]);
        const bf16 pb = (bf16)pv;
        ps[w][quad * 4 + r][j * 16 + l16] = pb;  // C-layout -> LDS
        psum[r] += (float)pb;  // sum the ROUNDED p for O/l consistency
      }
    }
#pragma unroll
    for (int r = 0; r < 4; ++r) {
      psum[r] += __shfl_xor(psum[r], 1);
      psum[r] += __shfl_xor(psum[r], 2);
      psum[r] += __shfl_xor(psum[r], 4);
      psum[r] += __shfl_xor(psum[r], 8);
      lrun[r] = lrun[r] * alpha[r] + psum[r];
    }
#pragma unroll
    for (int dt = 0; dt < 16; ++dt)
#pragma unroll
      for (int r = 0; r < 4; ++r) o[dt][r] *= alpha[r];

    // ---- O += P @ V ---- (same-wave DS in-order: no barrier needed for ps)
    bf16x8 pa[4];
#pragma unroll
    for (int k2 = 0; k2 < 4; ++k2)
      pa[k2] = *(const bf16x8*)&ps[w][l16][k2 * 32 + quad * 8];  // A-layout
#pragma unroll
    for (int k2 = 0; k2 < 4; ++k2) {
#pragma unroll
      for (int dt = 0; dt < 16; ++dt) {  // 16 independent chains
        const bf16x8 vf = *(const bf16x8*)&vs[dt * 16 + l16][k2 * 32 + quad * 8];
        o[dt] = MFMA16(pa[k2], vf, o[dt]);
      }
    }
    __syncthreads();  // before next iteration overwrites ks/vs
  }

  float inv[4];
#pragma unroll
  for (int r = 0; r < 4; ++r) inv[r] = 1.0f / lrun[r];
  const int orow0 = b * 2048 + qt * 64 + w * 16 + quad * 4;
#pragma unroll
  for (int dt = 0; dt < 16; ++dt)
#pragma unroll
    for (int r = 0; r < 4; ++r)
      out[(orow0 + r) * 256 + dt * 16 + l16] = o[dt][r] * inv[r];
}

// ---------------------------------------------------------------------------
// ws layout: Wt bf16 3x256x256 @0 (384 KB) | Q bf16 16384x256 (8 MB)
//            | K bf16 16384x256 (8 MB) | Vt bf16 8x256x2048 (8 MB)  ~24.6 MB
// ---------------------------------------------------------------------------
extern "C" void kernel_launch(void* const* d_in, const int* in_sizes, int n_in,
                              void* d_out, int out_size, void* d_ws,
                              size_t ws_size, hipStream_t stream) {
  const float* x = (const float*)d_in[0];
  const float* Wq = (const float*)d_in[1];
  const float* bq = (const float*)d_in[2];
  const float* Wk = (const float*)d_in[3];
  const float* bk = (const float*)d_in[4];
  const float* Wv = (const float*)d_in[5];
  const float* bv = (const float*)d_in[6];
  float* out = (float*)d_out;

  char* ws = (char*)d_ws;
  bf16* Wt = (bf16*)ws;
  bf16* Qws = (bf16*)(ws + 393216);
  bf16* Kws = (bf16*)(ws + 393216 + 8388608);
  bf16* Vws = (bf16*)(ws + 393216 + 16777216);

  prep_wt<<<768, 256, 0, stream>>>(Wq, Wk, Wv, Wt);
  proj_qkv<<<dim3(256, 3), 256, 0, stream>>>(x, Wt, bq, bk, bv, Qws, Kws, Vws);
  flash_attn<<<dim3(32, 8), 256, 0, stream>>>(Qws, Kws, Vws, out);
}

// Round 2
// 224.473 us; speedup vs baseline: 1.0513x; 1.0513x over previous
//
#include <hip/hip_runtime.h>

typedef __bf16 bf16;
typedef __bf16 bf16x4v __attribute__((ext_vector_type(4)));
typedef __bf16 bf16x8 __attribute__((ext_vector_type(8)));
typedef float f32x4 __attribute__((ext_vector_type(4)));
typedef short s16x4 __attribute__((ext_vector_type(4)));

#define MFMA_X32(A, B, C) __builtin_amdgcn_mfma_f32_16x16x32_bf16(A, B, C, 0, 0, 0)

// 16x16x16 bf16 MFMA: A/B = 4 bf16 per lane, A[m=lane&15][k=(lane>>4)*4+j].
// Crucial property: its A-layout k-index (quad*4+j) matches the 16x16x32
// C-layout row-index (quad*4+reg), so Sᵀ fragments feed PV with NO transpose.
#if __has_builtin(__builtin_amdgcn_mfma_f32_16x16x16_bf16)
static __device__ __forceinline__ f32x4 mfma_x16(bf16x4v a, bf16x4v b, f32x4 c) {
  return __builtin_amdgcn_mfma_f32_16x16x16_bf16(a, b, c, 0, 0, 0);
}
#else
static __device__ __forceinline__ f32x4 mfma_x16(bf16x4v a, bf16x4v b, f32x4 c) {
  return __builtin_amdgcn_mfma_f32_16x16x16bf16_1k(
      __builtin_bit_cast(s16x4, a), __builtin_bit_cast(s16x4, b), c, 0, 0, 0);
}
#endif

static __device__ __forceinline__ float fast_exp2(float x) {
  float r;
  asm volatile("v_exp_f32 %0, %1\n\ts_nop 0" : "=v"(r) : "v"(x));
  return r;
}

// async global->LDS, 16B/lane. LDS dest = wave-uniform base + lane*16 (HW).
static __device__ __forceinline__ void gll16(const void* g, void* l) {
  __builtin_amdgcn_global_load_lds(
      (const __attribute__((address_space(1))) void*)g,
      (__attribute__((address_space(3))) void*)l, 16, 0, 0);
}

// ---- workspace byte offsets ----
#define WT_OFF 0              // Wt bf16 [3][256 n][256 k]        (384 KB)
#define Q_OFF 393216          // Q' bf16 [16384][256] (pre-scaled) (8 MB)
#define K_OFF 8781824         // K  bf16 [16384][256]              (8 MB)
#define V_OFF 17170432        // Vc bf16 [8][128 tile][256 d][16]  (8 MB)

// ---------------------------------------------------------------------------
// Kernel 1: W [k][n] fp32 -> Wt bf16 [p][n][k] (MFMA B-frags 16B-contiguous)
// ---------------------------------------------------------------------------
__global__ __launch_bounds__(256) void prep_wt(const float* __restrict__ Wq,
                                               const float* __restrict__ Wk,
                                               const float* __restrict__ Wv,
                                               bf16* __restrict__ Wt) {
  const int idx = blockIdx.x * 256 + threadIdx.x;
  const int p = idx >> 16;
  const int rem = idx & 65535;  // k*256 + n
  const int k = rem >> 8, n = rem & 255;
  const float* W = (p == 0) ? Wq : ((p == 1) ? Wk : Wv);
  Wt[p * 65536 + n * 256 + k] = (bf16)W[rem];
}

// ---------------------------------------------------------------------------
// Kernel 2: fused QKV projection. ONE block reads its x tile once (fp32 HBM
// traffic 64 MB total instead of 192) and loops p = Q,K,V. Wt staged through
// LDS in 128-row halves (moves W traffic from L2 to LDS). Q is pre-scaled by
// log2(e)/sqrt(D) so flash scores are directly in the log2 domain. V is
// written in chunked layout Vc[b][s>>4][d][s&15] so flash can stage V tiles
// with contiguous 1024B global_load_lds units.
// ---------------------------------------------------------------------------
__global__ __launch_bounds__(256) void proj_qkv(const float* __restrict__ x,
                                                const float* __restrict__ bq,
                                                const float* __restrict__ bk,
                                                const float* __restrict__ bv,
                                                char* __restrict__ ws0) {
  __shared__ __align__(16) bf16 xs[64][264];
  __shared__ __align__(16) bf16 wth[128][264];
  const bf16* Wt = (const bf16*)(ws0 + WT_OFF);
  bf16* Qo = (bf16*)(ws0 + Q_OFF);
  bf16* Ko = (bf16*)(ws0 + K_OFF);
  bf16* Vc = (bf16*)(ws0 + V_OFF);
  const int t = threadIdx.x;
  const int rowbase = blockIdx.x * 64;

  {  // stage x tile -> bf16 LDS (float4 loads)
    const int rr = t >> 6, c4 = (t & 63) * 4;
#pragma unroll 4
    for (int i = 0; i < 16; ++i) {
      const int r = rr + i * 4;
      const float4 v = *(const float4*)&x[(rowbase + r) * 256 + c4];
      bf16x4v h;
      h[0] = (bf16)v.x; h[1] = (bf16)v.y; h[2] = (bf16)v.z; h[3] = (bf16)v.w;
      *(bf16x4v*)&xs[r][c4] = h;
    }
  }
  __syncthreads();
  const int lane = t & 63, w = t >> 6, l16 = lane & 15, quad = lane >> 4;

  bf16x8 a[8];  // persistent x A-fragments (wave's 16 rows, K=256)
#pragma unroll
  for (int kt = 0; kt < 8; ++kt)
    a[kt] = *(const bf16x8*)&xs[w * 16 + l16][kt * 32 + quad * 8];

  for (int p = 0; p < 3; ++p) {
    f32x4 acc[16];
#pragma unroll
    for (int nt = 0; nt < 16; ++nt) acc[nt] = f32x4{0.f, 0.f, 0.f, 0.f};
    for (int h = 0; h < 2; ++h) {
      __syncthreads();
#pragma unroll 4
      for (int i = 0; i < 16; ++i) {  // stage 128-row Wt half (64 KB)
        const int u = i * 256 + t;
        const int row = u >> 5, c8 = (u & 31) * 8;
        *(bf16x8*)&wth[row][c8] =
            *(const bf16x8*)&Wt[p * 65536 + (h * 128 + row) * 256 + c8];
      }
      __syncthreads();
#pragma unroll
      for (int kt = 0; kt < 8; ++kt)
#pragma unroll
        for (int ntl = 0; ntl < 8; ++ntl) {
          const bf16x8 bfr = *(const bf16x8*)&wth[ntl * 16 + l16][kt * 32 + quad * 8];
          acc[h * 8 + ntl] = MFMA_X32(a[kt], bfr, acc[h * 8 + ntl]);
        }
    }
    const float* bias = (p == 0) ? bq : ((p == 1) ? bk : bv);
    const float sc = (p == 0) ? 0.09016844005556021f : 1.0f;  // log2e/16
#pragma unroll
    for (int nt = 0; nt < 16; ++nt) {
      const int n = nt * 16 + l16;
      const float bb = bias[n];
#pragma unroll
      for (int r = 0; r < 4; ++r) {
        const int row = rowbase + w * 16 + quad * 4 + r;
        const bf16 hv = (bf16)((acc[nt][r] + bb) * sc);
        if (p == 0) {
          Qo[row * 256 + n] = hv;
        } else if (p == 1) {
          Ko[row * 256 + n] = hv;
        } else {
          const int b2 = row >> 11, s = row & 2047;
          Vc[b2 * 524288 + (s >> 4) * 4096 + n * 16 + (s & 15)] = hv;
        }
      }
    }
  }
}

// ---------------------------------------------------------------------------
// Kernel 3: flash attention. 512 threads = 8 waves = (qs in {0,1}, kq in
// {0..3}): wave owns 32 Q rows (2x16 subtiles, frags+O in regs) x 512 keys.
// Per iter: 16-key K+V chunks for all 4 kq staged via global_load_lds into a
// DOUBLE-buffered LDS region (2 x 65 KB; 16B pad per 1024B unit keeps bank
// spread uniform while preserving GLL contiguity). Sᵀ = K·Qᵀ via 16x16x32
// (C-layout: q on lane&15, key on quad*4+reg) -> softmax reductions need only
// 2 shfl_xor -> exp2'd bf16 C-frags ARE the 16x16x16 PV A-frags (no
// transpose, no P LDS round-trip). End: 4-way kq merge through LDS.
// ---------------------------------------------------------------------------
#define BUF_SZ 66560   // per double-buffer half: 4 kq * (K 8320 + V 8320)
#define SLOT_SZ 16640  // merge slot: 16 rows * (1024 + 16 pad)

__global__ __launch_bounds__(512, 2) void flash_attn(const char* __restrict__ ws0,
                                                     float* __restrict__ out) {
  __shared__ __align__(1024) char smem[137216];  // 2*BUF_SZ + 4KB ml
  const bf16* Qp = (const bf16*)(ws0 + Q_OFF);
  const int t = threadIdx.x;
  const int lane = t & 63, w = t >> 6;
  const int l16 = lane & 15, quad = lane >> 4;
  const int qs = w & 1, kq = w >> 1;
  const int b = blockIdx.x & 7;  // batch == XCD (L2 locality heuristic)
  const int qt = blockIdx.x >> 3;
  const int qrow0 = b * 2048 + qt * 64 + qs * 32;

  bf16x8 qf[2][8];  // Q' fragments, persistent
#pragma unroll
  for (int qsub = 0; qsub < 2; ++qsub)
#pragma unroll
    for (int kt = 0; kt < 8; ++kt)
      qf[qsub][kt] =
          *(const bf16x8*)&Qp[(qrow0 + qsub * 16 + l16) * 256 + kt * 32 + quad * 8];

  f32x4 o[2][16];
#pragma unroll
  for (int qsub = 0; qsub < 2; ++qsub)
#pragma unroll
    for (int dt = 0; dt < 16; ++dt) o[qsub][dt] = f32x4{0.f, 0.f, 0.f, 0.f};
  float m_[2] = {-1e30f, -1e30f}, l_[2] = {0.f, 0.f};

  // per-wave staging: 8 GLL units/iter (K: 2-key-row pairs; V: 1KB of a tile)
  unsigned goff[8], loff[8];
#pragma unroll
  for (int i = 0; i < 8; ++i) {
    const int u = w * 8 + i;
    const int kq2 = (u & 31) >> 3, e = u & 7;
    goff[i] = (u < 32 ? (unsigned)K_OFF : (unsigned)V_OFF) + b * 1048576u +
              kq2 * 262144u + e * 1024u + lane * 16u;
    loff[i] = (u < 32 ? 0u : 33280u) + kq2 * 8320u + e * 1040u;
  }
#pragma unroll
  for (int i = 0; i < 8; ++i) gll16(ws0 + goff[i], smem + loff[i]);  // prologue

  for (int it = 0; it < 32; ++it) {
    __syncthreads();  // drains vmcnt: chunk `it` resident in buf[it&1]
    const unsigned cur = (unsigned)(it & 1) * BUF_SZ;
    if (it + 1 < 32) {  // async prefetch of chunk it+1 overlaps compute
      const unsigned nxt = (unsigned)((it + 1) & 1) * BUF_SZ;
      const unsigned gadd = (unsigned)(it + 1) * 8192u;
#pragma unroll
      for (int i = 0; i < 8; ++i) gll16(ws0 + goff[i] + gadd, smem + nxt + loff[i]);
    }

    // ---- Sᵀ = K_chunk · Q'ᵀ  (16 keys x 32 q) ----
    const char* kb =
        smem + cur + kq * 8320 + (l16 >> 1) * 1040 + (l16 & 1) * 512 + quad * 16;
    f32x4 s0 = f32x4{0.f, 0.f, 0.f, 0.f}, s1 = s0;
#pragma unroll
    for (int kt = 0; kt < 8; ++kt) {
      const bf16x8 kf = *(const bf16x8*)(kb + kt * 64);  // A = K rows
      s0 = MFMA_X32(kf, qf[0][kt], s0);
      s1 = MFMA_X32(kf, qf[1][kt], s1);
    }

    // ---- online softmax (scores already log2-domain; q = l16) ----
    bf16x4v pa[2];
#pragma unroll
    for (int qsub = 0; qsub < 2; ++qsub) {
      const f32x4 s = qsub ? s1 : s0;
      float cm = fmaxf(fmaxf(s[0], s[1]), fmaxf(s[2], s[3]));
      cm = fmaxf(cm, __shfl_xor(cm, 16));
      cm = fmaxf(cm, __shfl_xor(cm, 32));
      const float mold = m_[qsub];
      const float mnew = fmaxf(mold, cm);
      bf16x4v pp;
      float ps = 0.f;
#pragma unroll
      for (int r = 0; r < 4; ++r) {
        const float e = fast_exp2(s[r] - mnew);
        const bf16 pb = (bf16)e;
        pp[r] = pb;
        ps += (float)pb;  // sum the ROUNDED p for O/l consistency
      }
      ps += __shfl_xor(ps, 16);
      ps += __shfl_xor(ps, 32);
      if (__any(mnew > mold)) {  // wave-uniform skip when max unchanged
        const float al = fast_exp2(mold - mnew);
        m_[qsub] = mnew;
        l_[qsub] = l_[qsub] * al + ps;
        float ar[4];
#pragma unroll
        for (int r = 0; r < 4; ++r)
          ar[r] = __shfl(al, (quad << 4) + (quad << 2) + r);  // q=l16 -> q=4quad+r
#pragma unroll
        for (int dt = 0; dt < 16; ++dt)
#pragma unroll
          for (int r = 0; r < 4; ++r) o[qsub][dt][r] *= ar[r];
      } else {
        l_[qsub] += ps;
      }
      pa[qsub] = pp;  // C-frag == 16x16x16 A-frag. No transpose.
    }

    // ---- O += P · V  (16x16x16; V B-frag = b64 from [d][key] tile) ----
    const char* vb = smem + cur + 33280 + kq * 8320 + l16 * 32 + quad * 8;
#pragma unroll
    for (int dt = 0; dt < 16; ++dt) {
      const bf16x4v vf = *(const bf16x4v*)(vb + (dt >> 1) * 1040 + (dt & 1) * 512);
      o[0][dt] = mfma_x16(pa[0], vf, o[0][dt]);
      o[1][dt] = mfma_x16(pa[1], vf, o[1][dt]);
    }
  }

  // ---- merge the 4 kq partials (scale by sigma, tree-sum through LDS) ----
  float* mlf = (float*)(smem + 133120);
  if (quad == 0) {
#pragma unroll
    for (int qsub = 0; qsub < 2; ++qsub) {
      const int base = ((kq * 2 + qs) * 2 + qsub) * 32;
      mlf[base + l16] = m_[qsub];
      mlf[base + 16 + l16] = l_[qsub];
    }
  }
  __syncthreads();
#pragma unroll
  for (int qsub = 0; qsub < 2; ++qsub) {
    float M = -1e30f, mk[4], lk[4];
#pragma unroll
    for (int k2 = 0; k2 < 4; ++k2) {
      const int base = ((k2 * 2 + qs) * 2 + qsub) * 32;
      mk[k2] = mlf[base + l16];
      lk[k2] = mlf[base + 16 + l16];
      M = fmaxf(M, mk[k2]);
    }
    float L = 0.f;
#pragma unroll
    for (int k2 = 0; k2 < 4; ++k2) L += lk[k2] * fast_exp2(mk[k2] - M);
    const float sg = fast_exp2(m_[qsub] - M) / L;
    float sr[4];
#pragma unroll
    for (int r = 0; r < 4; ++r) sr[r] = __shfl(sg, (quad << 4) + (quad << 2) + r);
#pragma unroll
    for (int dt = 0; dt < 16; ++dt)
#pragma unroll
      for (int r = 0; r < 4; ++r) o[qsub][dt][r] *= sr[r];
  }
  if (kq >= 2) {  // phase 1: kq 2,3 publish
#pragma unroll
    for (int qsub = 0; qsub < 2; ++qsub) {
      float* sb = (float*)(smem + ((kq - 2) * 4 + qs * 2 + qsub) * SLOT_SZ);
#pragma unroll
      for (int dt = 0; dt < 16; ++dt)
#pragma unroll
        for (int r = 0; r < 4; ++r)
          sb[(quad * 4 + r) * 260 + dt * 16 + l16] = o[qsub][dt][r];
    }
  }
  __syncthreads();
  if (kq < 2) {  // kq0 += kq2, kq1 += kq3
#pragma unroll
    for (int qsub = 0; qsub < 2; ++qsub) {
      const float* sb = (const float*)(smem + (kq * 4 + qs * 2 + qsub) * SLOT_SZ);
#pragma unroll
      for (int dt = 0; dt < 16; ++dt)
#pragma unroll
        for (int r = 0; r < 4; ++r)
          o[qsub][dt][r] += sb[(quad * 4 + r) * 260 + dt * 16 + l16];
    }
  }
  __syncthreads();
  if (kq == 1) {  // phase 2: kq1 publishes its partial sum
#pragma unroll
    for (int qsub = 0; qsub < 2; ++qsub) {
      float* sb = (float*)(smem + (qs * 2 + qsub) * SLOT_SZ);
#pragma unroll
      for (int dt = 0; dt < 16; ++dt)
#pragma unroll
        for (int r = 0; r < 4; ++r)
          sb[(quad * 4 + r) * 260 + dt * 16 + l16] = o[qsub][dt][r];
    }
  }
  __syncthreads();
  if (kq == 0) {  // final sum + store
#pragma unroll
    for (int qsub = 0; qsub < 2; ++qsub) {
      const float* sb = (const float*)(smem + (qs * 2 + qsub) * SLOT_SZ);
#pragma unroll
      for (int dt = 0; dt < 16; ++dt)
#pragma unroll
        for (int r = 0; r < 4; ++r) {
          const float v = o[qsub][dt][r] + sb[(quad * 4 + r) * 260 + dt * 16 + l16];
          out[(qrow0 + qsub * 16 + quad * 4 + r) * 256 + dt * 16 + l16] = v;
        }
    }
  }
}

extern "C" void kernel_launch(void* const* d_in, const int* in_sizes, int n_in,
                              void* d_out, int out_size, void* d_ws,
                              size_t ws_size, hipStream_t stream) {
  const float* x = (const float*)d_in[0];
  const float* Wq = (const float*)d_in[1];
  const float* bq = (const float*)d_in[2];
  const float* Wk = (const float*)d_in[3];
  const float* bk = (const float*)d_in[4];
  const float* Wv = (const float*)d_in[5];
  const float* bv = (const float*)d_in[6];
  float* out = (float*)d_out;
  char* ws = (char*)d_ws;

  prep_wt<<<768, 256, 0, stream>>>(Wq, Wk, Wv, (bf16*)(ws + WT_OFF));
  proj_qkv<<<256, 256, 0, stream>>>(x, bq, bk, bv, ws);
  flash_attn<<<256, 512, 0, stream>>>(ws, out);
}

// Round 3
// 176.526 us; speedup vs baseline: 1.3368x; 1.2716x over previous
//
#include <hip/hip_runtime.h>

typedef __bf16 bf16;
typedef __bf16 bf16x4v __attribute__((ext_vector_type(4)));
typedef __bf16 bf16x8 __attribute__((ext_vector_type(8)));
typedef float f32x4 __attribute__((ext_vector_type(4)));
typedef short s16x4 __attribute__((ext_vector_type(4)));

#define MFMA_X32(A, B, C) __builtin_amdgcn_mfma_f32_16x16x32_bf16(A, B, C, 0, 0, 0)

#if __has_builtin(__builtin_amdgcn_mfma_f32_16x16x16_bf16)
static __device__ __forceinline__ f32x4 mfma_x16(bf16x4v a, bf16x4v b, f32x4 c) {
  return __builtin_amdgcn_mfma_f32_16x16x16_bf16(a, b, c, 0, 0, 0);
}
#else
static __device__ __forceinline__ f32x4 mfma_x16(bf16x4v a, bf16x4v b, f32x4 c) {
  return __builtin_amdgcn_mfma_f32_16x16x16bf16_1k(
      __builtin_bit_cast(s16x4, a), __builtin_bit_cast(s16x4, b), c, 0, 0, 0);
}
#endif

static __device__ __forceinline__ float fast_exp2(float x) {
  float r;
  asm volatile("v_exp_f32 %0, %1\n\ts_nop 0" : "=v"(r) : "v"(x));
  return r;
}

static __device__ __forceinline__ void gll16(const void* g, void* l) {
  __builtin_amdgcn_global_load_lds(
      (const __attribute__((address_space(1))) void*)g,
      (__attribute__((address_space(3))) void*)l, 16, 0, 0);
}

// ---- workspace byte offsets ----
#define WT_OFF 0              // Wt bf16 [3][256 n][256 k]          (384 KB)
#define Q_OFF 393216          // Q' bf16 [16384][256] (pre-scaled)   (8 MB)
#define K_OFF 8781824         // Kc bf16 chunk-permuted (see below)  (8 MB)
#define V_OFF 17170432        // Vc bf16 chunk-permuted (see below)  (8 MB)
// Kc: per (b, 16-key chunk) 8KB block; element (key s, dim n) at
//   (n>>5)*512 + ((n>>3)&3)*128 + (s&15)*8 + (n&7)
//   => flash K-frag ds_read_b128 addr = base + kt*1024 + lane*16 (LINEAR).
// Vc: per (b, 16-key chunk) 8KB block; element (key s, dim d=n) at
//   (n>>4)*256 + ((s&15)>>2)*64 + (n&15)*4 + (s&3)
//   => flash V-frag ds_read_b64 addr = base + dt*512 + lane*8 (LINEAR).
// Linear-in-lane reads + linear GLL writes = zero bank conflicts by design.

// ---------------------------------------------------------------------------
// Kernel 1: W [k][n] fp32 -> Wt bf16 [p][n][k]
// ---------------------------------------------------------------------------
__global__ __launch_bounds__(256) void prep_wt(const float* __restrict__ Wq,
                                               const float* __restrict__ Wk,
                                               const float* __restrict__ Wv,
                                               bf16* __restrict__ Wt) {
  const int idx = blockIdx.x * 256 + threadIdx.x;
  const int p = idx >> 16;
  const int rem = idx & 65535;  // k*256 + n
  const int k = rem >> 8, n = rem & 255;
  const float* W = (p == 0) ? Wq : ((p == 1) ? Wk : Wv);
  Wt[p * 65536 + n * 256 + k] = (bf16)W[rem];
}

// ---------------------------------------------------------------------------
// Kernel 2: QKV projection, occupancy-first: 512 blocks x 4 waves, 32-row
// tiles, 50.7 KB LDS -> 3 blocks/CU = 12 waves/CU (R2 had 1 wave/SIMD and was
// latency-serialized). Wt staged per 64-col quarter; x A-frags persistent.
// Q pre-scaled by log2e/sqrt(D); K/V written in the flash LDS permutation.
// ---------------------------------------------------------------------------
__global__ __launch_bounds__(256, 3) void proj_qkv(const float* __restrict__ x,
                                                   const float* __restrict__ bq,
                                                   const float* __restrict__ bk,
                                                   const float* __restrict__ bv,
                                                   char* __restrict__ ws0) {
  __shared__ __align__(16) bf16 xs[32][264];   // 16.9 KB
  __shared__ __align__(16) bf16 wth[64][264];  // 33.8 KB
  const bf16* Wt = (const bf16*)(ws0 + WT_OFF);
  bf16* Qo = (bf16*)(ws0 + Q_OFF);
  bf16* Ko = (bf16*)(ws0 + K_OFF);
  bf16* Vc = (bf16*)(ws0 + V_OFF);
  const int t = threadIdx.x;
  const int rowbase = blockIdx.x * 32;

  {  // stage x tile (32x256 fp32 -> bf16), coalesced float4
    const int rr = t >> 6, c4 = (t & 63) * 4;
#pragma unroll
    for (int i = 0; i < 8; ++i) {
      const int r = i * 4 + rr;
      const float4 v = *(const float4*)&x[(rowbase + r) * 256 + c4];
      bf16x4v h;
      h[0] = (bf16)v.x; h[1] = (bf16)v.y; h[2] = (bf16)v.z; h[3] = (bf16)v.w;
      *(bf16x4v*)&xs[r][c4] = h;
    }
  }
  __syncthreads();
  const int lane = t & 63, w = t >> 6, l16 = lane & 15, quad = lane >> 4;
  const int rsub = (w & 1) * 16, csub = (w >> 1) * 32;

  bf16x8 a[8];  // persistent A-frags: wave's 16 rows, K=256
#pragma unroll
  for (int kt = 0; kt < 8; ++kt)
    a[kt] = *(const bf16x8*)&xs[rsub + l16][kt * 32 + quad * 8];

  for (int p = 0; p < 3; ++p) {
    const float* bias = (p == 0) ? bq : ((p == 1) ? bk : bv);
    const float sc = (p == 0) ? 0.09016844005556021f : 1.0f;  // log2e/16
    for (int q = 0; q < 4; ++q) {
      __syncthreads();  // previous quarter's frag reads done
#pragma unroll
      for (int i = 0; i < 8; ++i) {  // stage 64 n-rows of Wt (32 KB, L2-hot)
        const int u = i * 256 + t;
        const int row = u >> 5, c8 = (u & 31) * 8;
        *(bf16x8*)&wth[row][c8] =
            *(const bf16x8*)&Wt[p * 65536 + (q * 64 + row) * 256 + c8];
      }
      __syncthreads();
      f32x4 acc[2] = {f32x4{0.f, 0.f, 0.f, 0.f}, f32x4{0.f, 0.f, 0.f, 0.f}};
#pragma unroll
      for (int kt = 0; kt < 8; ++kt)
#pragma unroll
        for (int nt = 0; nt < 2; ++nt) {
          const bf16x8 bfr =
              *(const bf16x8*)&wth[csub + nt * 16 + l16][kt * 32 + quad * 8];
          acc[nt] = MFMA_X32(a[kt], bfr, acc[nt]);
        }
#pragma unroll
      for (int nt = 0; nt < 2; ++nt) {
        const int n = q * 64 + csub + nt * 16 + l16;
        const float bb = bias[n];
#pragma unroll
        for (int r = 0; r < 4; ++r) {
          const int row = rowbase + rsub + quad * 4 + r;  // C/D: row=quad*4+r
          const bf16 hv = (bf16)((acc[nt][r] + bb) * sc);
          if (p == 0) {
            Qo[row * 256 + n] = hv;
          } else {
            const int b2 = row >> 11, s = row & 2047;
            if (p == 1)
              Ko[b2 * 524288 + (s >> 4) * 4096 + (n >> 5) * 512 +
                 ((n >> 3) & 3) * 128 + (s & 15) * 8 + (n & 7)] = hv;
            else
              Vc[b2 * 524288 + (s >> 4) * 4096 + (n >> 4) * 256 +
                 (((s & 15) >> 2)) * 64 + (n & 15) * 4 + (s & 3)] = hv;
          }
        }
      }
    }
  }
}

// ---------------------------------------------------------------------------
// Kernel 3: flash attention. 8 waves = (qs, kq); wave = 32 Q rows x 512 keys.
// 16-key double-buffered chunks via global_load_lds; all LDS fragment reads
// are base+lane*16 / base+lane*8 LINEAR (conflict-free by construction).
// Sᵀ = K·Q'ᵀ (16x16x32) -> C-frags feed PV (16x16x16) with no transpose.
// ---------------------------------------------------------------------------
#define BUF_SZ 65536   // half: 4 kq * (K 8KB + V 8KB), no pads
#define SLOT_SZ 16640  // merge slot: 16 rows * 260 floats

__global__ __launch_bounds__(512, 2) void flash_attn(const char* __restrict__ ws0,
                                                     float* __restrict__ out) {
  __shared__ __align__(1024) char smem[135168];  // 2*BUF_SZ + merge scratch
  const bf16* Qp = (const bf16*)(ws0 + Q_OFF);
  const int t = threadIdx.x;
  const int lane = t & 63, w = t >> 6;
  const int l16 = lane & 15, quad = lane >> 4;
  const int qs = w & 1, kq = w >> 1;
  const int b = blockIdx.x & 7;  // batch == XCD round-robin: K/V L2-resident
  const int qt = blockIdx.x >> 3;
  const int qrow0 = b * 2048 + qt * 64 + qs * 32;

  bf16x8 qf[2][8];
#pragma unroll
  for (int qsub = 0; qsub < 2; ++qsub)
#pragma unroll
    for (int kt = 0; kt < 8; ++kt)
      qf[qsub][kt] =
          *(const bf16x8*)&Qp[(qrow0 + qsub * 16 + l16) * 256 + kt * 32 + quad * 8];

  f32x4 o[2][16];
#pragma unroll
  for (int qsub = 0; qsub < 2; ++qsub)
#pragma unroll
    for (int dt = 0; dt < 16; ++dt) o[qsub][dt] = f32x4{0.f, 0.f, 0.f, 0.f};
  float m_[2] = {-1e30f, -1e30f}, l_[2] = {0.f, 0.f};

  // staging assignment: 8 GLL units (1 KB each) per wave per iter
  unsigned goff[8], loff[8];
#pragma unroll
  for (int i = 0; i < 8; ++i) {
    const int u = w * 8 + i;
    const int kq2 = (u & 31) >> 3, e = u & 7;
    goff[i] = (u < 32 ? (unsigned)K_OFF : (unsigned)V_OFF) + b * 1048576u +
              kq2 * 262144u + e * 1024u + lane * 16u;
    loff[i] = kq2 * 16384u + (u < 32 ? 0u : 8192u) + e * 1024u;
  }
#pragma unroll
  for (int i = 0; i < 8; ++i) gll16(ws0 + goff[i], smem + loff[i]);

  for (int it = 0; it < 32; ++it) {
    __syncthreads();  // chunk `it` resident; prev-iter reads of `nxt` done
    const unsigned cur = (unsigned)(it & 1) * BUF_SZ;
    if (it + 1 < 32) {
      const unsigned nxt = (unsigned)((it + 1) & 1) * BUF_SZ;
      const unsigned gadd = (unsigned)(it + 1) * 8192u;
#pragma unroll
      for (int i = 0; i < 8; ++i) gll16(ws0 + goff[i] + gadd, smem + nxt + loff[i]);
    }

    // ---- Sᵀ = K_chunk · Q'ᵀ (16 keys x 32 q); K reads LINEAR b128 ----
    const char* kb = smem + cur + kq * 16384 + lane * 16;
    f32x4 s0 = f32x4{0.f, 0.f, 0.f, 0.f}, s1 = s0;
#pragma unroll
    for (int kt = 0; kt < 8; ++kt) {
      const bf16x8 kf = *(const bf16x8*)(kb + kt * 1024);
      s0 = MFMA_X32(kf, qf[0][kt], s0);
      s1 = MFMA_X32(kf, qf[1][kt], s1);
    }

    // ---- online softmax (log2 domain; q = l16, key = quad*4+r) ----
    bf16x4v pa[2];
#pragma unroll
    for (int qsub = 0; qsub < 2; ++qsub) {
      const f32x4 s = qsub ? s1 : s0;
      float cm = fmaxf(fmaxf(s[0], s[1]), fmaxf(s[2], s[3]));
      cm = fmaxf(cm, __shfl_xor(cm, 16));
      cm = fmaxf(cm, __shfl_xor(cm, 32));
      const float mold = m_[qsub];
      const float mnew = fmaxf(mold, cm);
      bf16x4v pp;
      float ps = 0.f;
#pragma unroll
      for (int r = 0; r < 4; ++r) {
        const float e = fast_exp2(s[r] - mnew);
        const bf16 pb = (bf16)e;
        pp[r] = pb;
        ps += (float)pb;  // sum ROUNDED p for O/l consistency
      }
      ps += __shfl_xor(ps, 16);
      ps += __shfl_xor(ps, 32);
      if (__any(mnew > mold)) {
        const float al = fast_exp2(mold - mnew);
        m_[qsub] = mnew;
        l_[qsub] = l_[qsub] * al + ps;
        float ar[4];
#pragma unroll
        for (int r = 0; r < 4; ++r)
          ar[r] = __shfl(al, (quad << 4) + (quad << 2) + r);
#pragma unroll
        for (int dt = 0; dt < 16; ++dt)
#pragma unroll
          for (int r = 0; r < 4; ++r) o[qsub][dt][r] *= ar[r];
      } else {
        l_[qsub] += ps;
      }
      pa[qsub] = pp;  // Sᵀ C-frag == PV A-frag
    }

    // ---- O += P · V; V reads LINEAR b64 ----
    const char* vb = smem + cur + kq * 16384 + 8192 + lane * 8;
#pragma unroll
    for (int dt = 0; dt < 16; ++dt) {
      const bf16x4v vf = *(const bf16x4v*)(vb + dt * 512);
      o[0][dt] = mfma_x16(pa[0], vf, o[0][dt]);
      o[1][dt] = mfma_x16(pa[1], vf, o[1][dt]);
    }
  }

  // ---- merge 4 kq partials ----
  float* mlf = (float*)(smem + 133120);  // beyond both buffers: no race
  if (quad == 0) {
#pragma unroll
    for (int qsub = 0; qsub < 2; ++qsub) {
      const int base = ((kq * 2 + qs) * 2 + qsub) * 32;
      mlf[base + l16] = m_[qsub];
      mlf[base + 16 + l16] = l_[qsub];
    }
  }
  __syncthreads();
#pragma unroll
  for (int qsub = 0; qsub < 2; ++qsub) {
    float M = -1e30f, mk[4], lk[4];
#pragma unroll
    for (int k2 = 0; k2 < 4; ++k2) {
      const int base = ((k2 * 2 + qs) * 2 + qsub) * 32;
      mk[k2] = mlf[base + l16];
      lk[k2] = mlf[base + 16 + l16];
      M = fmaxf(M, mk[k2]);
    }
    float L = 0.f;
#pragma unroll
    for (int k2 = 0; k2 < 4; ++k2) L += lk[k2] * fast_exp2(mk[k2] - M);
    const float sg = fast_exp2(m_[qsub] - M) / L;
    float sr[4];
#pragma unroll
    for (int r = 0; r < 4; ++r) sr[r] = __shfl(sg, (quad << 4) + (quad << 2) + r);
#pragma unroll
    for (int dt = 0; dt < 16; ++dt)
#pragma unroll
      for (int r = 0; r < 4; ++r) o[qsub][dt][r] *= sr[r];
  }
  if (kq >= 2) {
#pragma unroll
    for (int qsub = 0; qsub < 2; ++qsub) {
      float* sb = (float*)(smem + ((kq - 2) * 4 + qs * 2 + qsub) * SLOT_SZ);
#pragma unroll
      for (int dt = 0; dt < 16; ++dt)
#pragma unroll
        for (int r = 0; r < 4; ++r)
          sb[(quad * 4 + r) * 260 + dt * 16 + l16] = o[qsub][dt][r];
    }
  }
  __syncthreads();
  if (kq < 2) {
#pragma unroll
    for (int qsub = 0; qsub < 2; ++qsub) {
      const float* sb = (const float*)(smem + (kq * 4 + qs * 2 + qsub) * SLOT_SZ);
#pragma unroll
      for (int dt = 0; dt < 16; ++dt)
#pragma unroll
        for (int r = 0; r < 4; ++r)
          o[qsub][dt][r] += sb[(quad * 4 + r) * 260 + dt * 16 + l16];
    }
  }
  __syncthreads();
  if (kq == 1) {
#pragma unroll
    for (int qsub = 0; qsub < 2; ++qsub) {
      float* sb = (float*)(smem + (qs * 2 + qsub) * SLOT_SZ);
#pragma unroll
      for (int dt = 0; dt < 16; ++dt)
#pragma unroll
        for (int r = 0; r < 4; ++r)
          sb[(quad * 4 + r) * 260 + dt * 16 + l16] = o[qsub][dt][r];
    }
  }
  __syncthreads();
  if (kq == 0) {
#pragma unroll
    for (int qsub = 0; qsub < 2; ++qsub) {
      const float* sb = (const float*)(smem + (qs * 2 + qsub) * SLOT_SZ);
#pragma unroll
      for (int dt = 0; dt < 16; ++dt)
#pragma unroll
        for (int r = 0; r < 4; ++r) {
          const float v = o[qsub][dt][r] + sb[(quad * 4 + r) * 260 + dt * 16 + l16];
          out[(qrow0 + qsub * 16 + quad * 4 + r) * 256 + dt * 16 + l16] = v;
        }
    }
  }
}

extern "C" void kernel_launch(void* const* d_in, const int* in_sizes, int n_in,
                              void* d_out, int out_size, void* d_ws,
                              size_t ws_size, hipStream_t stream) {
  const float* x = (const float*)d_in[0];
  const float* Wq = (const float*)d_in[1];
  const float* bq = (const float*)d_in[2];
  const float* Wk = (const float*)d_in[3];
  const float* bk = (const float*)d_in[4];
  const float* Wv = (const float*)d_in[5];
  const float* bv = (const float*)d_in[6];
  float* out = (float*)d_out;
  char* ws = (char*)d_ws;

  prep_wt<<<768, 256, 0, stream>>>(Wq, Wk, Wv, (bf16*)(ws + WT_OFF));
  proj_qkv<<<512, 256, 0, stream>>>(x, bq, bk, bv, ws);
  flash_attn<<<256, 512, 0, stream>>>(ws, out);
}